// Round 5
// baseline (295.840 us; speedup 1.0000x reference)
//
#include <hip/hip_runtime.h>
#include <hip/hip_bf16.h>

// KoopmanOperators: B=16, N=64, T=8, sd=8, h=128, es=128, ud=32, rd=64, gd=32
// BT = 128, NODES = 8192, PAIRS = 524288
//
// Factorizations (exact affine algebra):
//   h_rel   = relu(P_i - P_j + reb1),            P = s @ reW1
//   pre_rel = enc_rel @ rpW[256:320] + A_i + B_j + rpb,
//             A = enc_obj @ rpW[0:128], B = enc_obj @ rpW[128:256]
//
// MFMA 16x16x32 (bf16 for node/comp, f16 for the pair path):
//   A-frag: lane l holds A[row][k], row = l&15, k = (l>>4)*8 + e (e=0..7)
//   B-frag: lane l holds B[k][col], col = l&15, k = (l>>4)*8 + e
//   C/D:    lane l reg r holds D[(l>>4)*4 + r][l&15]
// Inter-layer transpose bounces through XOR-swizzled LDS
// (granule = 16B, g' = g ^ (row&7)).
// k_comp is FUSED into k_pair (each pair-block owns exactly its 16 output rows).

typedef __bf16 bf16x8 __attribute__((ext_vector_type(8)));
typedef _Float16 half8 __attribute__((ext_vector_type(8)));
typedef float f32x4 __attribute__((ext_vector_type(4)));

static __device__ __forceinline__ half8 relu8(half8 x) {
    half8 z = {};
    return __builtin_elementwise_max(x, z);
}

// ---------------------------------------------------------------- k_prep
// pack weights into MFMA B-fragment order (bf16 for node/comp, f16 for pair)
__global__ __launch_bounds__(256) void k_prep(
    const float* __restrict__ sW1, const float* __restrict__ uW1,
    const float* __restrict__ reW1, const float* __restrict__ sW2,
    const float* __restrict__ uW2, const float* __restrict__ upW,
    const float* __restrict__ reW2, const float* __restrict__ rpW,
    const float* __restrict__ cW1, const float* __restrict__ cW2,
    const float* __restrict__ cW3,
    __bf16* __restrict__ Wl1f, __bf16* __restrict__ Ws2f,
    __bf16* __restrict__ Wu2f, __bf16* __restrict__ Wupf,
    __bf16* __restrict__ Wabf, _Float16* __restrict__ W2f,
    _Float16* __restrict__ Wbf, __bf16* __restrict__ Wc1f,
    __bf16* __restrict__ Wc2f, __bf16* __restrict__ Wc3f)
{
    const int tid  = blockIdx.x * 256 + threadIdx.x;
    const int nthr = gridDim.x * 256;

#define PACK(dst, CAST, NKT, NCT, EXPR)                             \
    for (int q = tid; q < (NKT) * (NCT) * 512; q += nthr) {         \
        const int f = q >> 9, rem = q & 511;                        \
        const int lane = rem >> 3, e = rem & 7;                     \
        const int kt = f / (NCT), ct = f % (NCT);                   \
        const int k = kt * 32 + (lane >> 4) * 8 + e;                \
        const int c = ct * 16 + (lane & 15);                        \
        (dst)[q] = (CAST)(EXPR);                                    \
        (void)k; (void)c;                                           \
    }

    PACK(Wl1f, __bf16, 1, 24, (k >= 8 ? 0.f :
        (c < 128 ? sW1[k * 128 + c] :
         c < 256 ? uW1[k * 128 + (c - 128)] : reW1[k * 128 + (c - 256)])))
    PACK(Ws2f, __bf16, 4, 8, sW2[k * 128 + c])
    PACK(Wu2f, __bf16, 4, 2, uW2[k * 32 + c])
    PACK(Wupf, __bf16, 5, 2, (k < 160 ? upW[k * 32 + c] : 0.f))
    PACK(Wabf, __bf16, 4, 8, (c < 64 ? rpW[k * 64 + c] : rpW[(128 + k) * 64 + (c - 64)]))
    PACK(W2f,  _Float16, 4, 4, reW2[k * 64 + c])
    PACK(Wbf,  _Float16, 2, 4, rpW[(256 + k) * 64 + c])
    PACK(Wc1f, __bf16, 7, 8, cW1[k * 128 + c])
    PACK(Wc2f, __bf16, 4, 8, cW2[k * 128 + c])
    PACK(Wc3f, __bf16, 4, 2, cW3[k * 32 + c])
#undef PACK
}

// ---------------------------------------------------------------- kernel 1
// per-node encoders via MFMA. 512 blocks x 512 thr (8 waves); 16 rows/block.
__global__ __launch_bounds__(512) void k_node(
    const float* __restrict__ states,
    const float* __restrict__ sb1, const float* __restrict__ sb2,
    const float* __restrict__ ub1, const float* __restrict__ ub2,
    const float* __restrict__ upb,
    const __bf16* __restrict__ Wl1f, const __bf16* __restrict__ Ws2f,
    const __bf16* __restrict__ Wu2f, const __bf16* __restrict__ Wupf,
    const __bf16* __restrict__ Wabf,
    _Float16* __restrict__ P_h, float* __restrict__ A_g,
    _Float16* __restrict__ Bh_g, __bf16* __restrict__ x_g)
{
    const int t = threadIdx.x;
    const int lane = t & 63;
    const int w = t >> 6;                 // 0..7
    const int lr = lane >> 4, lc = lane & 15;
    const int nb = blockIdx.x * 16;       // global row base

    __shared__ __bf16 s_h1hu[16 * 256];   // 8 KB
    __shared__ __bf16 s_eoeu[16 * 192];   // 6 KB

    // ---- layer-1 A-frag from states (K=8, zero-padded to 32)
    bf16x8 af1 = {};
    if (lr == 0) {
        const int rg = nb + lc;
        const int bt = rg >> 6, n = rg & 63;
        const int b = bt >> 3, ts = bt & 7;
        const float* sp = &states[((size_t)((b * 64 + n) * 8 + ts)) * 8];
        const float4 s0 = *reinterpret_cast<const float4*>(sp);
        const float4 s1 = *reinterpret_cast<const float4*>(sp + 4);
        af1[0] = (__bf16)s0.x; af1[1] = (__bf16)s0.y;
        af1[2] = (__bf16)s0.z; af1[3] = (__bf16)s0.w;
        af1[4] = (__bf16)s1.x; af1[5] = (__bf16)s1.y;
        af1[6] = (__bf16)s1.z; af1[7] = (__bf16)s1.w;
    }

    // ---- layer 1: 24 cts (0..7 h1, 8..15 hu, 16..23 P); 3 per wave
    #pragma unroll
    for (int ci = 0; ci < 3; ++ci) {
        const int ct = w * 3 + ci;
        const bf16x8 wf = *reinterpret_cast<const bf16x8*>(
            Wl1f + ((size_t)(ct * 64 + lane)) * 8);
        const float bias = (ct < 8) ? sb1[ct * 16 + lc]
                          : (ct < 16) ? ub1[(ct - 8) * 16 + lc] : 0.f;
        f32x4 acc = {bias, bias, bias, bias};
        acc = __builtin_amdgcn_mfma_f32_16x16x32_bf16(af1, wf, acc, 0, 0, 0);
        #pragma unroll
        for (int r = 0; r < 4; ++r) {
            const int jj = lr * 4 + r;
            if (ct < 16) {
                const int col = ct * 16 + lc;            // 0..255
                const int g = col >> 3;
                s_h1hu[jj * 256 + (((g ^ (jj & 7)) << 3) | (col & 7))] =
                    (__bf16)fmaxf(acc[r], 0.f);
            } else {
                P_h[(size_t)(nb + jj) * 128 + (ct - 16) * 16 + lc] =
                    (_Float16)acc[r];
            }
        }
    }
    __syncthreads();

    // ---- layer 2: eo ct = w (all waves); eu ct = w (waves 0,1)
    const int jr = lc;
    const int sw = lc & 7;
    bf16x8 h1f[4];
    #pragma unroll
    for (int kt = 0; kt < 4; ++kt)
        h1f[kt] = *reinterpret_cast<const bf16x8*>(
            &s_h1hu[jr * 256 + (((kt * 4 + lr) ^ sw) << 3)]);
    {
        const int ct = w;
        const float bias = sb2[ct * 16 + lc];
        f32x4 acc = {bias, bias, bias, bias};
        #pragma unroll
        for (int kt = 0; kt < 4; ++kt) {
            const bf16x8 wf = *reinterpret_cast<const bf16x8*>(
                Ws2f + ((size_t)((kt * 8 + ct) * 64 + lane)) * 8);
            acc = __builtin_amdgcn_mfma_f32_16x16x32_bf16(h1f[kt], wf, acc, 0, 0, 0);
        }
        #pragma unroll
        for (int r = 0; r < 4; ++r) {
            const int jj = lr * 4 + r;
            const int col = ct * 16 + lc;
            const __bf16 v = (__bf16)fmaxf(acc[r], 0.f);
            x_g[(size_t)(nb + jj) * 160 + col] = v;
            const int g = col >> 3;
            s_eoeu[jj * 192 + (((g ^ (jj & 7)) << 3) | (col & 7))] = v;
        }
    }
    if (w < 2) {
        bf16x8 huf[4];
        #pragma unroll
        for (int kt = 0; kt < 4; ++kt)
            huf[kt] = *reinterpret_cast<const bf16x8*>(
                &s_h1hu[jr * 256 + (((16 + kt * 4 + lr) ^ sw) << 3)]);
        const int ct = w;
        const float bias = ub2[ct * 16 + lc];
        f32x4 acc = {bias, bias, bias, bias};
        #pragma unroll
        for (int kt = 0; kt < 4; ++kt) {
            const bf16x8 wf = *reinterpret_cast<const bf16x8*>(
                Wu2f + ((size_t)((kt * 2 + ct) * 64 + lane)) * 8);
            acc = __builtin_amdgcn_mfma_f32_16x16x32_bf16(huf[kt], wf, acc, 0, 0, 0);
        }
        #pragma unroll
        for (int r = 0; r < 4; ++r) {
            const int jj = lr * 4 + r;
            const int col = 128 + ct * 16 + lc;          // eu region
            const int g = col >> 3;                      // 16..19
            s_eoeu[jj * 192 + (((g ^ (jj & 7)) << 3) | (col & 7))] = (__bf16)acc[r];
        }
    }
    __syncthreads();

    // ---- layer 3: obs_u ct = w-6 (waves 6,7); A|Bm ct = w (all waves)
    bf16x8 eof[5];
    #pragma unroll
    for (int kt = 0; kt < 4; ++kt)
        eof[kt] = *reinterpret_cast<const bf16x8*>(
            &s_eoeu[jr * 192 + (((kt * 4 + lr) ^ sw) << 3)]);
    eof[4] = *reinterpret_cast<const bf16x8*>(
        &s_eoeu[jr * 192 + (((16 + lr) ^ sw) << 3)]);

    if (w >= 6) {
        const int ct = w - 6;
        const float bias = upb[ct * 16 + lc];
        f32x4 acc = {bias, bias, bias, bias};
        #pragma unroll
        for (int kt = 0; kt < 5; ++kt) {
            const bf16x8 wf = *reinterpret_cast<const bf16x8*>(
                Wupf + ((size_t)((kt * 2 + ct) * 64 + lane)) * 8);
            acc = __builtin_amdgcn_mfma_f32_16x16x32_bf16(eof[kt], wf, acc, 0, 0, 0);
        }
        #pragma unroll
        for (int r = 0; r < 4; ++r) {
            const int rg = nb + lr * 4 + r;
            x_g[(size_t)rg * 160 + 128 + ct * 16 + lc] = (__bf16)fmaxf(acc[r], 0.f);
        }
    }
    {
        const int ct = w;                 // 0..3 -> A, 4..7 -> Bm
        f32x4 acc = {0.f, 0.f, 0.f, 0.f};
        #pragma unroll
        for (int kt = 0; kt < 4; ++kt) {
            const bf16x8 wf = *reinterpret_cast<const bf16x8*>(
                Wabf + ((size_t)((kt * 8 + ct) * 64 + lane)) * 8);
            acc = __builtin_amdgcn_mfma_f32_16x16x32_bf16(eof[kt], wf, acc, 0, 0, 0);
        }
        #pragma unroll
        for (int r = 0; r < 4; ++r) {
            const int rg = nb + lr * 4 + r;
            if (ct < 4) A_g[(size_t)rg * 64 + ct * 16 + lc] = acc[r];
            else        Bh_g[(size_t)rg * 64 + (ct - 4) * 16 + lc] = (_Float16)acc[r];
        }
    }
}

// ---------------------------------------------------------------- kernel 2
// pairwise relations (f16 MFMA) + FUSED composed MLP3 (bf16 MFMA).
// 512 blocks = (bt, i-group of 16); 8 waves x 2 i each.
__global__ __launch_bounds__(512, 6) void k_pairc(
    const float* __restrict__ states,
    const _Float16* __restrict__ P_h, const float* __restrict__ A_g,
    const _Float16* __restrict__ Bh_g, const __bf16* __restrict__ x_g,
    const float* __restrict__ reb1, const float* __restrict__ reb2,
    const float* __restrict__ rpb,
    const _Float16* __restrict__ W2f, const _Float16* __restrict__ Wbf,
    const float* __restrict__ cb1, const float* __restrict__ cb2,
    const float* __restrict__ cb3,
    const __bf16* __restrict__ Wc1f, const __bf16* __restrict__ Wc2f,
    const __bf16* __restrict__ Wc3f,
    float* __restrict__ out)
{
    const int t    = threadIdx.x;
    const int lane = t & 63;
    const int w    = t >> 6;             // 0..7
    const int lr   = lane >> 4;
    const int lc   = lane & 15;
    // XCD-aware remap: 4 consecutive logical blocks (same bt) share an XCD L2
    const int bid  = (blockIdx.x & 7) * 64 + (blockIdx.x >> 3);
    const int bt   = bid >> 2;
    const int ig   = bid & 3;
    const int b    = bt >> 3, tstep = bt & 7;
    const int rowb = bt * 64 + ig * 16;  // this block's 16 output rows

    __shared__ _Float16 s_pj[64 * 128];   // 16 KB (overlaid by comp bufs later)
    __shared__ _Float16 s_er[8][16 * 64]; // 16 KB, per-wave
    __shared__ _Float16 s_bm[64 * 72];    // 9 KB, padded rows
    __shared__ float    s_ai[16 * 64];    // 4 KB, A_i + rpb
    __shared__ _Float16 s_rb[128];        // reb1 (f16)
    __shared__ float    s_s0[64], s_s4[64];

    // ---- cooperative staging
    for (int idx = t; idx < 1024; idx += 512) {
        const int j = idx >> 4, g = idx & 15;
        const half8 v = *reinterpret_cast<const half8*>(
            P_h + (size_t)(bt * 64 + j) * 128 + g * 8);
        *reinterpret_cast<half8*>(&s_pj[j * 128 + ((g ^ (j & 7)) << 3)]) = v;
    }
    {
        const int j = t >> 3, c8 = (t & 7) * 8;
        if (t < 512)
            *reinterpret_cast<half8*>(&s_bm[j * 72 + c8]) =
                *reinterpret_cast<const half8*>(
                    Bh_g + (size_t)(bt * 64 + j) * 64 + c8);
    }
    for (int idx = t; idx < 1024; idx += 512) {
        const int il = idx >> 6, c = idx & 63;
        s_ai[idx] = A_g[(size_t)(rowb + il) * 64 + c] + rpb[c];
    }
    if (t < 128) s_rb[t] = (_Float16)reb1[t];
    if (t < 64) {
        const float* sp = &states[((size_t)((b * 64 + t) * 8 + tstep)) * 8];
        s_s0[t] = sp[0];
        s_s4[t] = sp[4];
    }

    // ---- per-wave weight fragments (f16, L2-hot)
    half8 w2f[4][4];
    #pragma unroll
    for (int kt = 0; kt < 4; ++kt)
        #pragma unroll
        for (int ct = 0; ct < 4; ++ct)
            w2f[kt][ct] = *reinterpret_cast<const half8*>(
                W2f + ((size_t)((kt * 4 + ct) * 64 + lane)) * 8);
    half8 wbf[2][4];
    #pragma unroll
    for (int kt = 0; kt < 2; ++kt)
        #pragma unroll
        for (int ct = 0; ct < 4; ++ct)
            wbf[kt][ct] = *reinterpret_cast<const half8*>(
                Wbf + ((size_t)((kt * 4 + ct) * 64 + lane)) * 8);
    float reb2c[4];
    #pragma unroll
    for (int ct = 0; ct < 4; ++ct) reb2c[ct] = reb2[ct * 16 + lc];

    __syncthreads();

    _Float16* er = s_er[w];
    float rag2[2][4];                     // reduced rel_agg, valid on lr==0

    for (int q = 0; q < 2; ++q) {
        const int il = w * 2 + q;         // block-local i
        const int i  = ig * 16 + il;      // bt-local i
        const int isw = i & 7;

        // pib = P_i + reb1 (f16 packed)
        half8 pib[4];
        #pragma unroll
        for (int kt = 0; kt < 4; ++kt) {
            const int g = kt * 4 + lr;
            const half8 pv = *reinterpret_cast<const half8*>(
                &s_pj[i * 128 + ((g ^ isw) << 3)]);
            const half8 rb = *reinterpret_cast<const half8*>(&s_rb[g * 8]);
            pib[kt] = pv + rb;
        }
        float aic[4];
        #pragma unroll
        for (int ct = 0; ct < 4; ++ct) aic[ct] = s_ai[il * 64 + ct * 16 + lc];
        const unsigned long long selm = __ballot(
            fabsf(s_s0[i] - s_s0[lane]) > 0.1f ||
            fabsf(s_s4[i] - s_s4[lane]) > 0.1f);

        float ragg[4] = {0.f, 0.f, 0.f, 0.f};

        for (int jt = 0; jt < 4; ++jt) {
            const int j = jt * 16 + lc;              // A-frag row (sender)
            const int jsw = j & 7;
            // h = relu(pib - P_j), f16 packed, one b128 per kt
            half8 af[4];
            #pragma unroll
            for (int kt = 0; kt < 4; ++kt) {
                const int g = (kt * 4 + lr) ^ jsw;
                const half8 pj = *reinterpret_cast<const half8*>(
                    &s_pj[j * 128 + (g << 3)]);
                af[kt] = relu8(pib[kt] - pj);
            }
            // GEMM1 tile: er = relu(h @ reW2 + reb2)
            #pragma unroll
            for (int ct = 0; ct < 4; ++ct) {
                f32x4 acc = {reb2c[ct], reb2c[ct], reb2c[ct], reb2c[ct]};
                #pragma unroll
                for (int kt = 0; kt < 4; ++kt)
                    acc = __builtin_amdgcn_mfma_f32_16x16x32_f16(
                        af[kt], w2f[kt][ct], acc, 0, 0, 0);
                #pragma unroll
                for (int r = 0; r < 4; ++r) {
                    const int jj2 = lr * 4 + r;      // tile-local row
                    const int c = ct * 16 + lc;
                    er[jj2 * 64 + ((((c >> 3) ^ (jj2 & 7)) << 3) | (c & 7))] =
                        (_Float16)fmaxf(acc[r], 0.f);
                }
            }
            // GEMM2 tile + epilogue
            half8 a2[2];
            #pragma unroll
            for (int kt = 0; kt < 2; ++kt) {
                const int g = (kt * 4 + lr) ^ (lc & 7);
                a2[kt] = *reinterpret_cast<const half8*>(&er[lc * 64 + (g << 3)]);
            }
            #pragma unroll
            for (int ct = 0; ct < 4; ++ct) {
                f32x4 acc = {aic[ct], aic[ct], aic[ct], aic[ct]};
                #pragma unroll
                for (int kt = 0; kt < 2; ++kt)
                    acc = __builtin_amdgcn_mfma_f32_16x16x32_f16(
                        a2[kt], wbf[kt][ct], acc, 0, 0, 0);
                #pragma unroll
                for (int r = 0; r < 4; ++r) {
                    const int jj = jt * 16 + lr * 4 + r;
                    const float bm = (float)s_bm[jj * 72 + ct * 16 + lc];
                    float v = fmaxf(acc[r] + bm, 0.f);
                    v = ((selm >> jj) & 1ull) ? v : 0.f;
                    ragg[ct] += v;
                }
            }
        }
        // cross-lane reduce over lr groups
        #pragma unroll
        for (int ct = 0; ct < 4; ++ct) {
            ragg[ct] += __shfl_xor(ragg[ct], 16);
            ragg[ct] += __shfl_xor(ragg[ct], 32);
            rag2[q][ct] = ragg[ct];
        }
    }
    __syncthreads();   // all waves done with s_pj -> overlay comp buffers

    // ================= fused composed MLP3 (bf16) on this block's 16 rows
    __bf16* s_x  = reinterpret_cast<__bf16*>(s_pj);            // 16*256
    __bf16* s_h1 = s_x + 16 * 256;                             // 16*128
    __bf16* s_h2 = s_h1 + 16 * 128;                            // 16*128

    // stage x (granules 0..19) from x_g
    for (int idx = t; idx < 320; idx += 512) {
        const int j = idx / 20, g = idx - j * 20;
        const bf16x8 v = *reinterpret_cast<const bf16x8*>(
            x_g + (size_t)(rowb + j) * 160 + g * 8);
        *reinterpret_cast<bf16x8*>(&s_x[j * 256 + ((g ^ (j & 7)) << 3)]) = v;
    }
    // rel_agg from registers (granules 20..27)
    if (lr == 0) {
        #pragma unroll
        for (int q = 0; q < 2; ++q) {
            const int il = w * 2 + q;
            #pragma unroll
            for (int ct = 0; ct < 4; ++ct) {
                const int c = ct * 16 + lc;
                const int gg = 20 + (c >> 3);
                s_x[il * 256 + ((gg ^ (il & 7)) << 3) + (c & 7)] =
                    (__bf16)rag2[q][ct];
            }
        }
    }
    __syncthreads();

    // ---- layer 1: K=224; ct = w
    const int jr = lc;
    const int sw = lc & 7;
    bf16x8 xf[7];
    #pragma unroll
    for (int kt = 0; kt < 7; ++kt)
        xf[kt] = *reinterpret_cast<const bf16x8*>(
            &s_x[jr * 256 + (((kt * 4 + lr) ^ sw) << 3)]);
    {
        const int ct = w;
        const float bias = cb1[ct * 16 + lc];
        f32x4 acc = {bias, bias, bias, bias};
        #pragma unroll
        for (int kt = 0; kt < 7; ++kt) {
            const bf16x8 wf = *reinterpret_cast<const bf16x8*>(
                Wc1f + ((size_t)((kt * 8 + ct) * 64 + lane)) * 8);
            acc = __builtin_amdgcn_mfma_f32_16x16x32_bf16(xf[kt], wf, acc, 0, 0, 0);
        }
        #pragma unroll
        for (int r = 0; r < 4; ++r) {
            const int jj = lr * 4 + r;
            const int col = ct * 16 + lc, g = col >> 3;
            s_h1[jj * 128 + (((g ^ (jj & 7)) << 3) | (col & 7))] =
                (__bf16)fmaxf(acc[r], 0.f);
        }
    }
    __syncthreads();

    // ---- layer 2: K=128; ct = w
    bf16x8 hf[4];
    #pragma unroll
    for (int kt = 0; kt < 4; ++kt)
        hf[kt] = *reinterpret_cast<const bf16x8*>(
            &s_h1[jr * 128 + (((kt * 4 + lr) ^ sw) << 3)]);
    {
        const int ct = w;
        const float bias = cb2[ct * 16 + lc];
        f32x4 acc = {bias, bias, bias, bias};
        #pragma unroll
        for (int kt = 0; kt < 4; ++kt) {
            const bf16x8 wf = *reinterpret_cast<const bf16x8*>(
                Wc2f + ((size_t)((kt * 8 + ct) * 64 + lane)) * 8);
            acc = __builtin_amdgcn_mfma_f32_16x16x32_bf16(hf[kt], wf, acc, 0, 0, 0);
        }
        #pragma unroll
        for (int r = 0; r < 4; ++r) {
            const int jj = lr * 4 + r;
            const int col = ct * 16 + lc, g = col >> 3;
            s_h2[jj * 128 + (((g ^ (jj & 7)) << 3) | (col & 7))] =
                (__bf16)fmaxf(acc[r], 0.f);
        }
    }
    __syncthreads();

    // ---- layer 3: K=128, N=32, no relu; waves 0,1
    if (w < 2) {
        bf16x8 h2f[4];
        #pragma unroll
        for (int kt = 0; kt < 4; ++kt)
            h2f[kt] = *reinterpret_cast<const bf16x8*>(
                &s_h2[jr * 128 + (((kt * 4 + lr) ^ sw) << 3)]);
        const int ct = w;
        const float bias = cb3[ct * 16 + lc];
        f32x4 acc = {bias, bias, bias, bias};
        #pragma unroll
        for (int kt = 0; kt < 4; ++kt) {
            const bf16x8 wf = *reinterpret_cast<const bf16x8*>(
                Wc3f + ((size_t)((kt * 2 + ct) * 64 + lane)) * 8);
            acc = __builtin_amdgcn_mfma_f32_16x16x32_bf16(h2f[kt], wf, acc, 0, 0, 0);
        }
        #pragma unroll
        for (int r = 0; r < 4; ++r) {
            const int rg = rowb + lr * 4 + r;
            out[(size_t)rg * 32 + ct * 16 + lc] = acc[r];
        }
    }
}

// ---------------------------------------------------------------- launch
extern "C" void kernel_launch(void* const* d_in, const int* in_sizes, int n_in,
                              void* d_out, int out_size, void* d_ws, size_t ws_size,
                              hipStream_t stream) {
    const float* states = (const float*)d_in[0];
    const float* sW1  = (const float*)d_in[2];
    const float* sb1  = (const float*)d_in[3];
    const float* sW2  = (const float*)d_in[4];
    const float* sb2  = (const float*)d_in[5];
    const float* uW1  = (const float*)d_in[6];
    const float* ub1  = (const float*)d_in[7];
    const float* uW2  = (const float*)d_in[8];
    const float* ub2  = (const float*)d_in[9];
    const float* upW  = (const float*)d_in[10];
    const float* upb  = (const float*)d_in[11];
    const float* reW1 = (const float*)d_in[12];
    const float* reb1 = (const float*)d_in[13];
    const float* reW2 = (const float*)d_in[14];
    const float* reb2 = (const float*)d_in[15];
    const float* rpW  = (const float*)d_in[16];
    const float* rpb  = (const float*)d_in[17];
    const float* cW1  = (const float*)d_in[18];
    const float* cb1  = (const float*)d_in[19];
    const float* cW2  = (const float*)d_in[20];
    const float* cb2  = (const float*)d_in[21];
    const float* cW3  = (const float*)d_in[22];
    const float* cb3  = (const float*)d_in[23];
    float* out = (float*)d_out;

    float* ws = (float*)d_ws;
    float* A_g = ws;                                  // 8192*64 f32
    _Float16* P_h  = (_Float16*)(A_g + 8192 * 64);    // 8192*128
    _Float16* Bh_g = P_h + 8192 * 128;                // 8192*64
    _Float16* W2f  = Bh_g + 8192 * 64;                // 16*512
    _Float16* Wbf  = W2f + 16 * 512;                  // 8*512
    __bf16* x_g  = (__bf16*)(Wbf + 8 * 512);          // 8192*160
    __bf16* Wl1f = x_g + 8192 * 160;                  // 24*512
    __bf16* Ws2f = Wl1f + 24 * 512;                   // 32*512
    __bf16* Wu2f = Ws2f + 32 * 512;                   // 8*512
    __bf16* Wupf = Wu2f + 8 * 512;                    // 10*512
    __bf16* Wabf = Wupf + 10 * 512;                   // 32*512
    __bf16* Wc1f = Wabf + 32 * 512;                   // 56*512
    __bf16* Wc2f = Wc1f + 56 * 512;                   // 32*512
    __bf16* Wc3f = Wc2f + 32 * 512;                   // 8*512

    k_prep<<<64, 256, 0, stream>>>(sW1, uW1, reW1, sW2, uW2, upW, reW2, rpW,
                                   cW1, cW2, cW3,
                                   Wl1f, Ws2f, Wu2f, Wupf, Wabf, W2f, Wbf,
                                   Wc1f, Wc2f, Wc3f);
    k_node<<<512, 512, 0, stream>>>(states, sb1, sb2, ub1, ub2, upb,
                                    Wl1f, Ws2f, Wu2f, Wupf, Wabf,
                                    P_h, A_g, Bh_g, x_g);
    k_pairc<<<512, 512, 0, stream>>>(states, P_h, A_g, Bh_g, x_g,
                                     reb1, reb2, rpb, W2f, Wbf,
                                     cb1, cb2, cb3, Wc1f, Wc2f, Wc3f, out);
}

// Round 6
// 244.365 us; speedup vs baseline: 1.2106x; 1.2106x over previous
//
#include <hip/hip_runtime.h>
#include <hip/hip_bf16.h>

// KoopmanOperators: B=16, N=64, T=8, sd=8, h=128, es=128, ud=32, rd=64, gd=32
// BT = 128, NODES = 8192, PAIRS = 524288
//
// Factorizations (exact affine algebra):
//   h_rel   = relu(P_i - P_j + reb1),            P = s @ reW1
//   pre_rel = enc_rel @ rpW[256:320] + A_i + B_j + rpb,
//             A = enc_obj @ rpW[0:128], B = enc_obj @ rpW[128:256]
//
// MFMA 16x16x32 (bf16 for node/comp, f16 for the pair path):
//   A-frag: lane l holds A[row][k], row = l&15, k = (l>>4)*8 + e (e=0..7)
//   B-frag: lane l holds B[k][col], col = l&15, k = (l>>4)*8 + e
//   C/D:    lane l reg r holds D[(l>>4)*4 + r][l&15]
// Inter-layer transpose bounces through XOR-swizzled LDS
// (granule = 16B, g' = g ^ (row&7)).
// k_comp is FUSED into k_pair (each pair-block owns exactly its 16 output rows).
//
// NOTE (round-5 post-mortem): launch_bounds min-waves must keep the VGPR cap
// >= ~128 — the preloaded weight fragments (w2f 64 + wbf 32 VGPR) + working
// set spill to scratch below that, producing 500+ MB of HBM spill traffic.
// (512,4) = cap 128, proven spill-free in round 4.

typedef __bf16 bf16x8 __attribute__((ext_vector_type(8)));
typedef _Float16 half8 __attribute__((ext_vector_type(8)));
typedef float f32x4 __attribute__((ext_vector_type(4)));

static __device__ __forceinline__ half8 relu8(half8 x) {
    half8 z = {};
    return __builtin_elementwise_max(x, z);
}

// ---------------------------------------------------------------- k_prep
// pack weights into MFMA B-fragment order (bf16 for node/comp, f16 for pair)
__global__ __launch_bounds__(256) void k_prep(
    const float* __restrict__ sW1, const float* __restrict__ uW1,
    const float* __restrict__ reW1, const float* __restrict__ sW2,
    const float* __restrict__ uW2, const float* __restrict__ upW,
    const float* __restrict__ reW2, const float* __restrict__ rpW,
    const float* __restrict__ cW1, const float* __restrict__ cW2,
    const float* __restrict__ cW3,
    __bf16* __restrict__ Wl1f, __bf16* __restrict__ Ws2f,
    __bf16* __restrict__ Wu2f, __bf16* __restrict__ Wupf,
    __bf16* __restrict__ Wabf, _Float16* __restrict__ W2f,
    _Float16* __restrict__ Wbf, __bf16* __restrict__ Wc1f,
    __bf16* __restrict__ Wc2f, __bf16* __restrict__ Wc3f)
{
    const int tid  = blockIdx.x * 256 + threadIdx.x;
    const int nthr = gridDim.x * 256;

#define PACK(dst, CAST, NKT, NCT, EXPR)                             \
    for (int q = tid; q < (NKT) * (NCT) * 512; q += nthr) {         \
        const int f = q >> 9, rem = q & 511;                        \
        const int lane = rem >> 3, e = rem & 7;                     \
        const int kt = f / (NCT), ct = f % (NCT);                   \
        const int k = kt * 32 + (lane >> 4) * 8 + e;                \
        const int c = ct * 16 + (lane & 15);                        \
        (dst)[q] = (CAST)(EXPR);                                    \
        (void)k; (void)c;                                           \
    }

    PACK(Wl1f, __bf16, 1, 24, (k >= 8 ? 0.f :
        (c < 128 ? sW1[k * 128 + c] :
         c < 256 ? uW1[k * 128 + (c - 128)] : reW1[k * 128 + (c - 256)])))
    PACK(Ws2f, __bf16, 4, 8, sW2[k * 128 + c])
    PACK(Wu2f, __bf16, 4, 2, uW2[k * 32 + c])
    PACK(Wupf, __bf16, 5, 2, (k < 160 ? upW[k * 32 + c] : 0.f))
    PACK(Wabf, __bf16, 4, 8, (c < 64 ? rpW[k * 64 + c] : rpW[(128 + k) * 64 + (c - 64)]))
    PACK(W2f,  _Float16, 4, 4, reW2[k * 64 + c])
    PACK(Wbf,  _Float16, 2, 4, rpW[(256 + k) * 64 + c])
    PACK(Wc1f, __bf16, 7, 8, cW1[k * 128 + c])
    PACK(Wc2f, __bf16, 4, 8, cW2[k * 128 + c])
    PACK(Wc3f, __bf16, 4, 2, cW3[k * 32 + c])
#undef PACK
}

// ---------------------------------------------------------------- kernel 1
// per-node encoders via MFMA. 512 blocks x 512 thr (8 waves); 16 rows/block.
__global__ __launch_bounds__(512) void k_node(
    const float* __restrict__ states,
    const float* __restrict__ sb1, const float* __restrict__ sb2,
    const float* __restrict__ ub1, const float* __restrict__ ub2,
    const float* __restrict__ upb,
    const __bf16* __restrict__ Wl1f, const __bf16* __restrict__ Ws2f,
    const __bf16* __restrict__ Wu2f, const __bf16* __restrict__ Wupf,
    const __bf16* __restrict__ Wabf,
    _Float16* __restrict__ P_h, float* __restrict__ A_g,
    _Float16* __restrict__ Bh_g, __bf16* __restrict__ x_g)
{
    const int t = threadIdx.x;
    const int lane = t & 63;
    const int w = t >> 6;                 // 0..7
    const int lr = lane >> 4, lc = lane & 15;
    const int nb = blockIdx.x * 16;       // global row base

    __shared__ __bf16 s_h1hu[16 * 256];   // 8 KB
    __shared__ __bf16 s_eoeu[16 * 192];   // 6 KB

    // ---- layer-1 A-frag from states (K=8, zero-padded to 32)
    bf16x8 af1 = {};
    if (lr == 0) {
        const int rg = nb + lc;
        const int bt = rg >> 6, n = rg & 63;
        const int b = bt >> 3, ts = bt & 7;
        const float* sp = &states[((size_t)((b * 64 + n) * 8 + ts)) * 8];
        const float4 s0 = *reinterpret_cast<const float4*>(sp);
        const float4 s1 = *reinterpret_cast<const float4*>(sp + 4);
        af1[0] = (__bf16)s0.x; af1[1] = (__bf16)s0.y;
        af1[2] = (__bf16)s0.z; af1[3] = (__bf16)s0.w;
        af1[4] = (__bf16)s1.x; af1[5] = (__bf16)s1.y;
        af1[6] = (__bf16)s1.z; af1[7] = (__bf16)s1.w;
    }

    // ---- layer 1: 24 cts (0..7 h1, 8..15 hu, 16..23 P); 3 per wave
    #pragma unroll
    for (int ci = 0; ci < 3; ++ci) {
        const int ct = w * 3 + ci;
        const bf16x8 wf = *reinterpret_cast<const bf16x8*>(
            Wl1f + ((size_t)(ct * 64 + lane)) * 8);
        const float bias = (ct < 8) ? sb1[ct * 16 + lc]
                          : (ct < 16) ? ub1[(ct - 8) * 16 + lc] : 0.f;
        f32x4 acc = {bias, bias, bias, bias};
        acc = __builtin_amdgcn_mfma_f32_16x16x32_bf16(af1, wf, acc, 0, 0, 0);
        #pragma unroll
        for (int r = 0; r < 4; ++r) {
            const int jj = lr * 4 + r;
            if (ct < 16) {
                const int col = ct * 16 + lc;            // 0..255
                const int g = col >> 3;
                s_h1hu[jj * 256 + (((g ^ (jj & 7)) << 3) | (col & 7))] =
                    (__bf16)fmaxf(acc[r], 0.f);
            } else {
                P_h[(size_t)(nb + jj) * 128 + (ct - 16) * 16 + lc] =
                    (_Float16)acc[r];
            }
        }
    }
    __syncthreads();

    // ---- layer 2: eo ct = w (all waves); eu ct = w (waves 0,1)
    const int jr = lc;
    const int sw = lc & 7;
    bf16x8 h1f[4];
    #pragma unroll
    for (int kt = 0; kt < 4; ++kt)
        h1f[kt] = *reinterpret_cast<const bf16x8*>(
            &s_h1hu[jr * 256 + (((kt * 4 + lr) ^ sw) << 3)]);
    {
        const int ct = w;
        const float bias = sb2[ct * 16 + lc];
        f32x4 acc = {bias, bias, bias, bias};
        #pragma unroll
        for (int kt = 0; kt < 4; ++kt) {
            const bf16x8 wf = *reinterpret_cast<const bf16x8*>(
                Ws2f + ((size_t)((kt * 8 + ct) * 64 + lane)) * 8);
            acc = __builtin_amdgcn_mfma_f32_16x16x32_bf16(h1f[kt], wf, acc, 0, 0, 0);
        }
        #pragma unroll
        for (int r = 0; r < 4; ++r) {
            const int jj = lr * 4 + r;
            const int col = ct * 16 + lc;
            const __bf16 v = (__bf16)fmaxf(acc[r], 0.f);
            x_g[(size_t)(nb + jj) * 160 + col] = v;
            const int g = col >> 3;
            s_eoeu[jj * 192 + (((g ^ (jj & 7)) << 3) | (col & 7))] = v;
        }
    }
    if (w < 2) {
        bf16x8 huf[4];
        #pragma unroll
        for (int kt = 0; kt < 4; ++kt)
            huf[kt] = *reinterpret_cast<const bf16x8*>(
                &s_h1hu[jr * 256 + (((16 + kt * 4 + lr) ^ sw) << 3)]);
        const int ct = w;
        const float bias = ub2[ct * 16 + lc];
        f32x4 acc = {bias, bias, bias, bias};
        #pragma unroll
        for (int kt = 0; kt < 4; ++kt) {
            const bf16x8 wf = *reinterpret_cast<const bf16x8*>(
                Wu2f + ((size_t)((kt * 2 + ct) * 64 + lane)) * 8);
            acc = __builtin_amdgcn_mfma_f32_16x16x32_bf16(huf[kt], wf, acc, 0, 0, 0);
        }
        #pragma unroll
        for (int r = 0; r < 4; ++r) {
            const int jj = lr * 4 + r;
            const int col = 128 + ct * 16 + lc;          // eu region
            const int g = col >> 3;                      // 16..19
            s_eoeu[jj * 192 + (((g ^ (jj & 7)) << 3) | (col & 7))] = (__bf16)acc[r];
        }
    }
    __syncthreads();

    // ---- layer 3: obs_u ct = w-6 (waves 6,7); A|Bm ct = w (all waves)
    bf16x8 eof[5];
    #pragma unroll
    for (int kt = 0; kt < 4; ++kt)
        eof[kt] = *reinterpret_cast<const bf16x8*>(
            &s_eoeu[jr * 192 + (((kt * 4 + lr) ^ sw) << 3)]);
    eof[4] = *reinterpret_cast<const bf16x8*>(
        &s_eoeu[jr * 192 + (((16 + lr) ^ sw) << 3)]);

    if (w >= 6) {
        const int ct = w - 6;
        const float bias = upb[ct * 16 + lc];
        f32x4 acc = {bias, bias, bias, bias};
        #pragma unroll
        for (int kt = 0; kt < 5; ++kt) {
            const bf16x8 wf = *reinterpret_cast<const bf16x8*>(
                Wupf + ((size_t)((kt * 2 + ct) * 64 + lane)) * 8);
            acc = __builtin_amdgcn_mfma_f32_16x16x32_bf16(eof[kt], wf, acc, 0, 0, 0);
        }
        #pragma unroll
        for (int r = 0; r < 4; ++r) {
            const int rg = nb + lr * 4 + r;
            x_g[(size_t)rg * 160 + 128 + ct * 16 + lc] = (__bf16)fmaxf(acc[r], 0.f);
        }
    }
    {
        const int ct = w;                 // 0..3 -> A, 4..7 -> Bm
        f32x4 acc = {0.f, 0.f, 0.f, 0.f};
        #pragma unroll
        for (int kt = 0; kt < 4; ++kt) {
            const bf16x8 wf = *reinterpret_cast<const bf16x8*>(
                Wabf + ((size_t)((kt * 8 + ct) * 64 + lane)) * 8);
            acc = __builtin_amdgcn_mfma_f32_16x16x32_bf16(eof[kt], wf, acc, 0, 0, 0);
        }
        #pragma unroll
        for (int r = 0; r < 4; ++r) {
            const int rg = nb + lr * 4 + r;
            if (ct < 4) A_g[(size_t)rg * 64 + ct * 16 + lc] = acc[r];
            else        Bh_g[(size_t)rg * 64 + (ct - 4) * 16 + lc] = (_Float16)acc[r];
        }
    }
}

// ---------------------------------------------------------------- kernel 2
// pairwise relations (f16 MFMA) + FUSED composed MLP3 (bf16 MFMA).
// 512 blocks = (bt, i-group of 16); 8 waves x 2 i each.
// launch_bounds (512,4): VGPR cap 128 — do NOT raise min-waves (spills!).
__global__ __launch_bounds__(512, 4) void k_pairc(
    const float* __restrict__ states,
    const _Float16* __restrict__ P_h, const float* __restrict__ A_g,
    const _Float16* __restrict__ Bh_g, const __bf16* __restrict__ x_g,
    const float* __restrict__ reb1, const float* __restrict__ reb2,
    const float* __restrict__ rpb,
    const _Float16* __restrict__ W2f, const _Float16* __restrict__ Wbf,
    const float* __restrict__ cb1, const float* __restrict__ cb2,
    const float* __restrict__ cb3,
    const __bf16* __restrict__ Wc1f, const __bf16* __restrict__ Wc2f,
    const __bf16* __restrict__ Wc3f,
    float* __restrict__ out)
{
    const int t    = threadIdx.x;
    const int lane = t & 63;
    const int w    = t >> 6;             // 0..7
    const int lr   = lane >> 4;
    const int lc   = lane & 15;
    // XCD-aware remap: 4 consecutive logical blocks (same bt) share an XCD L2
    const int bid  = (blockIdx.x & 7) * 64 + (blockIdx.x >> 3);
    const int bt   = bid >> 2;
    const int ig   = bid & 3;
    const int b    = bt >> 3, tstep = bt & 7;
    const int rowb = bt * 64 + ig * 16;  // this block's 16 output rows

    __shared__ _Float16 s_pj[64 * 128];   // 16 KB (overlaid by comp bufs later)
    __shared__ _Float16 s_er[8][16 * 64]; // 16 KB, per-wave
    __shared__ _Float16 s_bm[64 * 72];    // 9 KB, padded rows
    __shared__ float    s_ai[16 * 64];    // 4 KB, A_i + rpb
    __shared__ _Float16 s_rb[128];        // reb1 (f16)
    __shared__ float    s_s0[64], s_s4[64];

    // ---- cooperative staging
    for (int idx = t; idx < 1024; idx += 512) {
        const int j = idx >> 4, g = idx & 15;
        const half8 v = *reinterpret_cast<const half8*>(
            P_h + (size_t)(bt * 64 + j) * 128 + g * 8);
        *reinterpret_cast<half8*>(&s_pj[j * 128 + ((g ^ (j & 7)) << 3)]) = v;
    }
    {
        const int j = t >> 3, c8 = (t & 7) * 8;
        if (t < 512)
            *reinterpret_cast<half8*>(&s_bm[j * 72 + c8]) =
                *reinterpret_cast<const half8*>(
                    Bh_g + (size_t)(bt * 64 + j) * 64 + c8);
    }
    for (int idx = t; idx < 1024; idx += 512) {
        const int il = idx >> 6, c = idx & 63;
        s_ai[idx] = A_g[(size_t)(rowb + il) * 64 + c] + rpb[c];
    }
    if (t < 128) s_rb[t] = (_Float16)reb1[t];
    if (t < 64) {
        const float* sp = &states[((size_t)((b * 64 + t) * 8 + tstep)) * 8];
        s_s0[t] = sp[0];
        s_s4[t] = sp[4];
    }

    // ---- per-wave weight fragments (f16, L2-hot)
    half8 w2f[4][4];
    #pragma unroll
    for (int kt = 0; kt < 4; ++kt)
        #pragma unroll
        for (int ct = 0; ct < 4; ++ct)
            w2f[kt][ct] = *reinterpret_cast<const half8*>(
                W2f + ((size_t)((kt * 4 + ct) * 64 + lane)) * 8);
    half8 wbf[2][4];
    #pragma unroll
    for (int kt = 0; kt < 2; ++kt)
        #pragma unroll
        for (int ct = 0; ct < 4; ++ct)
            wbf[kt][ct] = *reinterpret_cast<const half8*>(
                Wbf + ((size_t)((kt * 4 + ct) * 64 + lane)) * 8);
    float reb2c[4];
    #pragma unroll
    for (int ct = 0; ct < 4; ++ct) reb2c[ct] = reb2[ct * 16 + lc];

    __syncthreads();

    _Float16* er = s_er[w];
    float rag2[2][4];                     // reduced rel_agg, valid on lr==0

    for (int q = 0; q < 2; ++q) {
        const int il = w * 2 + q;         // block-local i
        const int i  = ig * 16 + il;      // bt-local i
        const int isw = i & 7;

        // pib = P_i + reb1 (f16 packed)
        half8 pib[4];
        #pragma unroll
        for (int kt = 0; kt < 4; ++kt) {
            const int g = kt * 4 + lr;
            const half8 pv = *reinterpret_cast<const half8*>(
                &s_pj[i * 128 + ((g ^ isw) << 3)]);
            const half8 rb = *reinterpret_cast<const half8*>(&s_rb[g * 8]);
            pib[kt] = pv + rb;
        }
        float aic[4];
        #pragma unroll
        for (int ct = 0; ct < 4; ++ct) aic[ct] = s_ai[il * 64 + ct * 16 + lc];
        const unsigned long long selm = __ballot(
            fabsf(s_s0[i] - s_s0[lane]) > 0.1f ||
            fabsf(s_s4[i] - s_s4[lane]) > 0.1f);

        float ragg[4] = {0.f, 0.f, 0.f, 0.f};

        for (int jt = 0; jt < 4; ++jt) {
            const int j = jt * 16 + lc;              // A-frag row (sender)
            const int jsw = j & 7;
            // h = relu(pib - P_j), f16 packed, one b128 per kt
            half8 af[4];
            #pragma unroll
            for (int kt = 0; kt < 4; ++kt) {
                const int g = (kt * 4 + lr) ^ jsw;
                const half8 pj = *reinterpret_cast<const half8*>(
                    &s_pj[j * 128 + (g << 3)]);
                af[kt] = relu8(pib[kt] - pj);
            }
            // GEMM1 tile: er = relu(h @ reW2 + reb2)
            #pragma unroll
            for (int ct = 0; ct < 4; ++ct) {
                f32x4 acc = {reb2c[ct], reb2c[ct], reb2c[ct], reb2c[ct]};
                #pragma unroll
                for (int kt = 0; kt < 4; ++kt)
                    acc = __builtin_amdgcn_mfma_f32_16x16x32_f16(
                        af[kt], w2f[kt][ct], acc, 0, 0, 0);
                #pragma unroll
                for (int r = 0; r < 4; ++r) {
                    const int jj2 = lr * 4 + r;      // tile-local row
                    const int c = ct * 16 + lc;
                    er[jj2 * 64 + ((((c >> 3) ^ (jj2 & 7)) << 3) | (c & 7))] =
                        (_Float16)fmaxf(acc[r], 0.f);
                }
            }
            // GEMM2 tile + epilogue
            half8 a2[2];
            #pragma unroll
            for (int kt = 0; kt < 2; ++kt) {
                const int g = (kt * 4 + lr) ^ (lc & 7);
                a2[kt] = *reinterpret_cast<const half8*>(&er[lc * 64 + (g << 3)]);
            }
            #pragma unroll
            for (int ct = 0; ct < 4; ++ct) {
                f32x4 acc = {aic[ct], aic[ct], aic[ct], aic[ct]};
                #pragma unroll
                for (int kt = 0; kt < 2; ++kt)
                    acc = __builtin_amdgcn_mfma_f32_16x16x32_f16(
                        a2[kt], wbf[kt][ct], acc, 0, 0, 0);
                #pragma unroll
                for (int r = 0; r < 4; ++r) {
                    const int jj = jt * 16 + lr * 4 + r;
                    const float bm = (float)s_bm[jj * 72 + ct * 16 + lc];
                    float v = fmaxf(acc[r] + bm, 0.f);
                    v = ((selm >> jj) & 1ull) ? v : 0.f;
                    ragg[ct] += v;
                }
            }
        }
        // cross-lane reduce over lr groups
        #pragma unroll
        for (int ct = 0; ct < 4; ++ct) {
            ragg[ct] += __shfl_xor(ragg[ct], 16);
            ragg[ct] += __shfl_xor(ragg[ct], 32);
            rag2[q][ct] = ragg[ct];
        }
    }
    __syncthreads();   // all waves done with s_pj -> overlay comp buffers

    // ================= fused composed MLP3 (bf16) on this block's 16 rows
    __bf16* s_x  = reinterpret_cast<__bf16*>(s_pj);            // 16*256
    __bf16* s_h1 = s_x + 16 * 256;                             // 16*128
    __bf16* s_h2 = s_h1 + 16 * 128;                            // 16*128

    // stage x (granules 0..19) from x_g
    for (int idx = t; idx < 320; idx += 512) {
        const int j = idx / 20, g = idx - j * 20;
        const bf16x8 v = *reinterpret_cast<const bf16x8*>(
            x_g + (size_t)(rowb + j) * 160 + g * 8);
        *reinterpret_cast<bf16x8*>(&s_x[j * 256 + ((g ^ (j & 7)) << 3)]) = v;
    }
    // rel_agg from registers (granules 20..27)
    if (lr == 0) {
        #pragma unroll
        for (int q = 0; q < 2; ++q) {
            const int il = w * 2 + q;
            #pragma unroll
            for (int ct = 0; ct < 4; ++ct) {
                const int c = ct * 16 + lc;
                const int gg = 20 + (c >> 3);
                s_x[il * 256 + ((gg ^ (il & 7)) << 3) + (c & 7)] =
                    (__bf16)rag2[q][ct];
            }
        }
    }
    __syncthreads();

    // ---- layer 1: K=224; ct = w
    const int jr = lc;
    const int sw = lc & 7;
    bf16x8 xf[7];
    #pragma unroll
    for (int kt = 0; kt < 7; ++kt)
        xf[kt] = *reinterpret_cast<const bf16x8*>(
            &s_x[jr * 256 + (((kt * 4 + lr) ^ sw) << 3)]);
    {
        const int ct = w;
        const float bias = cb1[ct * 16 + lc];
        f32x4 acc = {bias, bias, bias, bias};
        #pragma unroll
        for (int kt = 0; kt < 7; ++kt) {
            const bf16x8 wf = *reinterpret_cast<const bf16x8*>(
                Wc1f + ((size_t)((kt * 8 + ct) * 64 + lane)) * 8);
            acc = __builtin_amdgcn_mfma_f32_16x16x32_bf16(xf[kt], wf, acc, 0, 0, 0);
        }
        #pragma unroll
        for (int r = 0; r < 4; ++r) {
            const int jj = lr * 4 + r;
            const int col = ct * 16 + lc, g = col >> 3;
            s_h1[jj * 128 + (((g ^ (jj & 7)) << 3) | (col & 7))] =
                (__bf16)fmaxf(acc[r], 0.f);
        }
    }
    __syncthreads();

    // ---- layer 2: K=128; ct = w
    bf16x8 hf[4];
    #pragma unroll
    for (int kt = 0; kt < 4; ++kt)
        hf[kt] = *reinterpret_cast<const bf16x8*>(
            &s_h1[jr * 128 + (((kt * 4 + lr) ^ sw) << 3)]);
    {
        const int ct = w;
        const float bias = cb2[ct * 16 + lc];
        f32x4 acc = {bias, bias, bias, bias};
        #pragma unroll
        for (int kt = 0; kt < 4; ++kt) {
            const bf16x8 wf = *reinterpret_cast<const bf16x8*>(
                Wc2f + ((size_t)((kt * 8 + ct) * 64 + lane)) * 8);
            acc = __builtin_amdgcn_mfma_f32_16x16x32_bf16(hf[kt], wf, acc, 0, 0, 0);
        }
        #pragma unroll
        for (int r = 0; r < 4; ++r) {
            const int jj = lr * 4 + r;
            const int col = ct * 16 + lc, g = col >> 3;
            s_h2[jj * 128 + (((g ^ (jj & 7)) << 3) | (col & 7))] =
                (__bf16)fmaxf(acc[r], 0.f);
        }
    }
    __syncthreads();

    // ---- layer 3: K=128, N=32, no relu; waves 0,1
    if (w < 2) {
        bf16x8 h2f[4];
        #pragma unroll
        for (int kt = 0; kt < 4; ++kt)
            h2f[kt] = *reinterpret_cast<const bf16x8*>(
                &s_h2[jr * 128 + (((kt * 4 + lr) ^ sw) << 3)]);
        const int ct = w;
        const float bias = cb3[ct * 16 + lc];
        f32x4 acc = {bias, bias, bias, bias};
        #pragma unroll
        for (int kt = 0; kt < 4; ++kt) {
            const bf16x8 wf = *reinterpret_cast<const bf16x8*>(
                Wc3f + ((size_t)((kt * 2 + ct) * 64 + lane)) * 8);
            acc = __builtin_amdgcn_mfma_f32_16x16x32_bf16(h2f[kt], wf, acc, 0, 0, 0);
        }
        #pragma unroll
        for (int r = 0; r < 4; ++r) {
            const int rg = rowb + lr * 4 + r;
            out[(size_t)rg * 32 + ct * 16 + lc] = acc[r];
        }
    }
}

// ---------------------------------------------------------------- launch
extern "C" void kernel_launch(void* const* d_in, const int* in_sizes, int n_in,
                              void* d_out, int out_size, void* d_ws, size_t ws_size,
                              hipStream_t stream) {
    const float* states = (const float*)d_in[0];
    const float* sW1  = (const float*)d_in[2];
    const float* sb1  = (const float*)d_in[3];
    const float* sW2  = (const float*)d_in[4];
    const float* sb2  = (const float*)d_in[5];
    const float* uW1  = (const float*)d_in[6];
    const float* ub1  = (const float*)d_in[7];
    const float* uW2  = (const float*)d_in[8];
    const float* ub2  = (const float*)d_in[9];
    const float* upW  = (const float*)d_in[10];
    const float* upb  = (const float*)d_in[11];
    const float* reW1 = (const float*)d_in[12];
    const float* reb1 = (const float*)d_in[13];
    const float* reW2 = (const float*)d_in[14];
    const float* reb2 = (const float*)d_in[15];
    const float* rpW  = (const float*)d_in[16];
    const float* rpb  = (const float*)d_in[17];
    const float* cW1  = (const float*)d_in[18];
    const float* cb1  = (const float*)d_in[19];
    const float* cW2  = (const float*)d_in[20];
    const float* cb2  = (const float*)d_in[21];
    const float* cW3  = (const float*)d_in[22];
    const float* cb3  = (const float*)d_in[23];
    float* out = (float*)d_out;

    float* ws = (float*)d_ws;
    float* A_g = ws;                                  // 8192*64 f32
    _Float16* P_h  = (_Float16*)(A_g + 8192 * 64);    // 8192*128
    _Float16* Bh_g = P_h + 8192 * 128;                // 8192*64
    _Float16* W2f  = Bh_g + 8192 * 64;                // 16*512
    _Float16* Wbf  = W2f + 16 * 512;                  // 8*512
    __bf16* x_g  = (__bf16*)(Wbf + 8 * 512);          // 8192*160
    __bf16* Wl1f = x_g + 8192 * 160;                  // 24*512
    __bf16* Ws2f = Wl1f + 24 * 512;                   // 32*512
    __bf16* Wu2f = Ws2f + 32 * 512;                   // 8*512
    __bf16* Wupf = Wu2f + 8 * 512;                    // 10*512
    __bf16* Wabf = Wupf + 10 * 512;                   // 32*512
    __bf16* Wc1f = Wabf + 32 * 512;                   // 56*512
    __bf16* Wc2f = Wc1f + 56 * 512;                   // 32*512
    __bf16* Wc3f = Wc2f + 32 * 512;                   // 8*512

    k_prep<<<64, 256, 0, stream>>>(sW1, uW1, reW1, sW2, uW2, upW, reW2, rpW,
                                   cW1, cW2, cW3,
                                   Wl1f, Ws2f, Wu2f, Wupf, Wabf, W2f, Wbf,
                                   Wc1f, Wc2f, Wc3f);
    k_node<<<512, 512, 0, stream>>>(states, sb1, sb2, ub1, ub2, upb,
                                    Wl1f, Ws2f, Wu2f, Wupf, Wabf,
                                    P_h, A_g, Bh_g, x_g);
    k_pairc<<<512, 512, 0, stream>>>(states, P_h, A_g, Bh_g, x_g,
                                     reb1, reb2, rpb, W2f, Wbf,
                                     cb1, cb2, cb3, Wc1f, Wc2f, Wc3f, out);
}

// Round 7
// 147.212 us; speedup vs baseline: 2.0096x; 1.6600x over previous
//
#include <hip/hip_runtime.h>
#include <hip/hip_bf16.h>

// KoopmanOperators: B=16, N=64, T=8, sd=8, h=128, es=128, ud=32, rd=64, gd=32
// BT = 128, NODES = 8192, PAIRS = 524288
//
// Factorizations (exact affine algebra):
//   h_rel   = relu(P_i - P_j + reb1),            P = s @ reW1
//   pre_rel = enc_rel @ rpW[256:320] + A_i + B_j + rpb,
//             A = enc_obj @ rpW[0:128], B = enc_obj @ rpW[128:256]
//
// MFMA 16x16x32 (bf16 for node/comp, f16 for the pair path):
//   A-frag: lane l holds A[row][k], row = l&15, k = (l>>4)*8 + e (e=0..7)
//   B-frag: lane l holds B[k][col], col = l&15, k = (l>>4)*8 + e
//   C/D:    lane l reg r holds D[(l>>4)*4 + r][l&15]
// Inter-layer transpose bounces through XOR-swizzled LDS
// (granule = 16B, g' = g ^ (row&7)).
// k_comp is FUSED into k_pair (each pair-block owns exactly its 16 output rows).
//
// LAUNCH-BOUNDS SEMANTICS (measured rounds 4-6): the 2nd arg is min BLOCKS
// per CU (CUDA semantics). VGPR cap = 512 / (arg * wavesPerBlock / 4).
//   (512,6) -> cap 40  (observed VGPR 40,  538 MB spill traffic)
//   (512,4) -> cap 64  (observed VGPR 64,  371 MB spill traffic)
//   (512,2) -> cap 128 (round 4 proved this state fits 128 spill-free)
// Do NOT raise the 2nd arg above 2 for 512-thread blocks.

typedef __bf16 bf16x8 __attribute__((ext_vector_type(8)));
typedef _Float16 half8 __attribute__((ext_vector_type(8)));
typedef float f32x4 __attribute__((ext_vector_type(4)));

static __device__ __forceinline__ half8 relu8(half8 x) {
    half8 z = {};
    return __builtin_elementwise_max(x, z);
}

// ---------------------------------------------------------------- k_prep
// pack weights into MFMA B-fragment order (bf16 for node/comp, f16 for pair)
__global__ __launch_bounds__(256) void k_prep(
    const float* __restrict__ sW1, const float* __restrict__ uW1,
    const float* __restrict__ reW1, const float* __restrict__ sW2,
    const float* __restrict__ uW2, const float* __restrict__ upW,
    const float* __restrict__ reW2, const float* __restrict__ rpW,
    const float* __restrict__ cW1, const float* __restrict__ cW2,
    const float* __restrict__ cW3,
    __bf16* __restrict__ Wl1f, __bf16* __restrict__ Ws2f,
    __bf16* __restrict__ Wu2f, __bf16* __restrict__ Wupf,
    __bf16* __restrict__ Wabf, _Float16* __restrict__ W2f,
    _Float16* __restrict__ Wbf, __bf16* __restrict__ Wc1f,
    __bf16* __restrict__ Wc2f, __bf16* __restrict__ Wc3f)
{
    const int tid  = blockIdx.x * 256 + threadIdx.x;
    const int nthr = gridDim.x * 256;

#define PACK(dst, CAST, NKT, NCT, EXPR)                             \
    for (int q = tid; q < (NKT) * (NCT) * 512; q += nthr) {         \
        const int f = q >> 9, rem = q & 511;                        \
        const int lane = rem >> 3, e = rem & 7;                     \
        const int kt = f / (NCT), ct = f % (NCT);                   \
        const int k = kt * 32 + (lane >> 4) * 8 + e;                \
        const int c = ct * 16 + (lane & 15);                        \
        (dst)[q] = (CAST)(EXPR);                                    \
        (void)k; (void)c;                                           \
    }

    PACK(Wl1f, __bf16, 1, 24, (k >= 8 ? 0.f :
        (c < 128 ? sW1[k * 128 + c] :
         c < 256 ? uW1[k * 128 + (c - 128)] : reW1[k * 128 + (c - 256)])))
    PACK(Ws2f, __bf16, 4, 8, sW2[k * 128 + c])
    PACK(Wu2f, __bf16, 4, 2, uW2[k * 32 + c])
    PACK(Wupf, __bf16, 5, 2, (k < 160 ? upW[k * 32 + c] : 0.f))
    PACK(Wabf, __bf16, 4, 8, (c < 64 ? rpW[k * 64 + c] : rpW[(128 + k) * 64 + (c - 64)]))
    PACK(W2f,  _Float16, 4, 4, reW2[k * 64 + c])
    PACK(Wbf,  _Float16, 2, 4, rpW[(256 + k) * 64 + c])
    PACK(Wc1f, __bf16, 7, 8, cW1[k * 128 + c])
    PACK(Wc2f, __bf16, 4, 8, cW2[k * 128 + c])
    PACK(Wc3f, __bf16, 4, 2, cW3[k * 32 + c])
#undef PACK
}

// ---------------------------------------------------------------- kernel 1
// per-node encoders via MFMA. 512 blocks x 512 thr (8 waves); 16 rows/block.
__global__ __launch_bounds__(512) void k_node(
    const float* __restrict__ states,
    const float* __restrict__ sb1, const float* __restrict__ sb2,
    const float* __restrict__ ub1, const float* __restrict__ ub2,
    const float* __restrict__ upb,
    const __bf16* __restrict__ Wl1f, const __bf16* __restrict__ Ws2f,
    const __bf16* __restrict__ Wu2f, const __bf16* __restrict__ Wupf,
    const __bf16* __restrict__ Wabf,
    _Float16* __restrict__ P_h, float* __restrict__ A_g,
    _Float16* __restrict__ Bh_g, __bf16* __restrict__ x_g)
{
    const int t = threadIdx.x;
    const int lane = t & 63;
    const int w = t >> 6;                 // 0..7
    const int lr = lane >> 4, lc = lane & 15;
    const int nb = blockIdx.x * 16;       // global row base

    __shared__ __bf16 s_h1hu[16 * 256];   // 8 KB
    __shared__ __bf16 s_eoeu[16 * 192];   // 6 KB

    // ---- layer-1 A-frag from states (K=8, zero-padded to 32)
    bf16x8 af1 = {};
    if (lr == 0) {
        const int rg = nb + lc;
        const int bt = rg >> 6, n = rg & 63;
        const int b = bt >> 3, ts = bt & 7;
        const float* sp = &states[((size_t)((b * 64 + n) * 8 + ts)) * 8];
        const float4 s0 = *reinterpret_cast<const float4*>(sp);
        const float4 s1 = *reinterpret_cast<const float4*>(sp + 4);
        af1[0] = (__bf16)s0.x; af1[1] = (__bf16)s0.y;
        af1[2] = (__bf16)s0.z; af1[3] = (__bf16)s0.w;
        af1[4] = (__bf16)s1.x; af1[5] = (__bf16)s1.y;
        af1[6] = (__bf16)s1.z; af1[7] = (__bf16)s1.w;
    }

    // ---- layer 1: 24 cts (0..7 h1, 8..15 hu, 16..23 P); 3 per wave
    #pragma unroll
    for (int ci = 0; ci < 3; ++ci) {
        const int ct = w * 3 + ci;
        const bf16x8 wf = *reinterpret_cast<const bf16x8*>(
            Wl1f + ((size_t)(ct * 64 + lane)) * 8);
        const float bias = (ct < 8) ? sb1[ct * 16 + lc]
                          : (ct < 16) ? ub1[(ct - 8) * 16 + lc] : 0.f;
        f32x4 acc = {bias, bias, bias, bias};
        acc = __builtin_amdgcn_mfma_f32_16x16x32_bf16(af1, wf, acc, 0, 0, 0);
        #pragma unroll
        for (int r = 0; r < 4; ++r) {
            const int jj = lr * 4 + r;
            if (ct < 16) {
                const int col = ct * 16 + lc;            // 0..255
                const int g = col >> 3;
                s_h1hu[jj * 256 + (((g ^ (jj & 7)) << 3) | (col & 7))] =
                    (__bf16)fmaxf(acc[r], 0.f);
            } else {
                P_h[(size_t)(nb + jj) * 128 + (ct - 16) * 16 + lc] =
                    (_Float16)acc[r];
            }
        }
    }
    __syncthreads();

    // ---- layer 2: eo ct = w (all waves); eu ct = w (waves 0,1)
    const int jr = lc;
    const int sw = lc & 7;
    bf16x8 h1f[4];
    #pragma unroll
    for (int kt = 0; kt < 4; ++kt)
        h1f[kt] = *reinterpret_cast<const bf16x8*>(
            &s_h1hu[jr * 256 + (((kt * 4 + lr) ^ sw) << 3)]);
    {
        const int ct = w;
        const float bias = sb2[ct * 16 + lc];
        f32x4 acc = {bias, bias, bias, bias};
        #pragma unroll
        for (int kt = 0; kt < 4; ++kt) {
            const bf16x8 wf = *reinterpret_cast<const bf16x8*>(
                Ws2f + ((size_t)((kt * 8 + ct) * 64 + lane)) * 8);
            acc = __builtin_amdgcn_mfma_f32_16x16x32_bf16(h1f[kt], wf, acc, 0, 0, 0);
        }
        #pragma unroll
        for (int r = 0; r < 4; ++r) {
            const int jj = lr * 4 + r;
            const int col = ct * 16 + lc;
            const __bf16 v = (__bf16)fmaxf(acc[r], 0.f);
            x_g[(size_t)(nb + jj) * 160 + col] = v;
            const int g = col >> 3;
            s_eoeu[jj * 192 + (((g ^ (jj & 7)) << 3) | (col & 7))] = v;
        }
    }
    if (w < 2) {
        bf16x8 huf[4];
        #pragma unroll
        for (int kt = 0; kt < 4; ++kt)
            huf[kt] = *reinterpret_cast<const bf16x8*>(
                &s_h1hu[jr * 256 + (((16 + kt * 4 + lr) ^ sw) << 3)]);
        const int ct = w;
        const float bias = ub2[ct * 16 + lc];
        f32x4 acc = {bias, bias, bias, bias};
        #pragma unroll
        for (int kt = 0; kt < 4; ++kt) {
            const bf16x8 wf = *reinterpret_cast<const bf16x8*>(
                Wu2f + ((size_t)((kt * 2 + ct) * 64 + lane)) * 8);
            acc = __builtin_amdgcn_mfma_f32_16x16x32_bf16(huf[kt], wf, acc, 0, 0, 0);
        }
        #pragma unroll
        for (int r = 0; r < 4; ++r) {
            const int jj = lr * 4 + r;
            const int col = 128 + ct * 16 + lc;          // eu region
            const int g = col >> 3;                      // 16..19
            s_eoeu[jj * 192 + (((g ^ (jj & 7)) << 3) | (col & 7))] = (__bf16)acc[r];
        }
    }
    __syncthreads();

    // ---- layer 3: obs_u ct = w-6 (waves 6,7); A|Bm ct = w (all waves)
    bf16x8 eof[5];
    #pragma unroll
    for (int kt = 0; kt < 4; ++kt)
        eof[kt] = *reinterpret_cast<const bf16x8*>(
            &s_eoeu[jr * 192 + (((kt * 4 + lr) ^ sw) << 3)]);
    eof[4] = *reinterpret_cast<const bf16x8*>(
        &s_eoeu[jr * 192 + (((16 + lr) ^ sw) << 3)]);

    if (w >= 6) {
        const int ct = w - 6;
        const float bias = upb[ct * 16 + lc];
        f32x4 acc = {bias, bias, bias, bias};
        #pragma unroll
        for (int kt = 0; kt < 5; ++kt) {
            const bf16x8 wf = *reinterpret_cast<const bf16x8*>(
                Wupf + ((size_t)((kt * 2 + ct) * 64 + lane)) * 8);
            acc = __builtin_amdgcn_mfma_f32_16x16x32_bf16(eof[kt], wf, acc, 0, 0, 0);
        }
        #pragma unroll
        for (int r = 0; r < 4; ++r) {
            const int rg = nb + lr * 4 + r;
            x_g[(size_t)rg * 160 + 128 + ct * 16 + lc] = (__bf16)fmaxf(acc[r], 0.f);
        }
    }
    {
        const int ct = w;                 // 0..3 -> A, 4..7 -> Bm
        f32x4 acc = {0.f, 0.f, 0.f, 0.f};
        #pragma unroll
        for (int kt = 0; kt < 4; ++kt) {
            const bf16x8 wf = *reinterpret_cast<const bf16x8*>(
                Wabf + ((size_t)((kt * 8 + ct) * 64 + lane)) * 8);
            acc = __builtin_amdgcn_mfma_f32_16x16x32_bf16(eof[kt], wf, acc, 0, 0, 0);
        }
        #pragma unroll
        for (int r = 0; r < 4; ++r) {
            const int rg = nb + lr * 4 + r;
            if (ct < 4) A_g[(size_t)rg * 64 + ct * 16 + lc] = acc[r];
            else        Bh_g[(size_t)rg * 64 + (ct - 4) * 16 + lc] = (_Float16)acc[r];
        }
    }
}

// ---------------------------------------------------------------- kernel 2
// pairwise relations (f16 MFMA) + FUSED composed MLP3 (bf16 MFMA).
// 512 blocks = (bt, i-group of 16); 8 waves x 2 i each.
// launch_bounds (512,2): 2 blocks/CU -> VGPR cap 128 (see header note).
__global__ __launch_bounds__(512, 2) void k_pairc(
    const float* __restrict__ states,
    const _Float16* __restrict__ P_h, const float* __restrict__ A_g,
    const _Float16* __restrict__ Bh_g, const __bf16* __restrict__ x_g,
    const float* __restrict__ reb1, const float* __restrict__ reb2,
    const float* __restrict__ rpb,
    const _Float16* __restrict__ W2f, const _Float16* __restrict__ Wbf,
    const float* __restrict__ cb1, const float* __restrict__ cb2,
    const float* __restrict__ cb3,
    const __bf16* __restrict__ Wc1f, const __bf16* __restrict__ Wc2f,
    const __bf16* __restrict__ Wc3f,
    float* __restrict__ out)
{
    const int t    = threadIdx.x;
    const int lane = t & 63;
    const int w    = t >> 6;             // 0..7
    const int lr   = lane >> 4;
    const int lc   = lane & 15;
    // XCD-aware remap: 4 consecutive logical blocks (same bt) share an XCD L2
    const int bid  = (blockIdx.x & 7) * 64 + (blockIdx.x >> 3);
    const int bt   = bid >> 2;
    const int ig   = bid & 3;
    const int b    = bt >> 3, tstep = bt & 7;
    const int rowb = bt * 64 + ig * 16;  // this block's 16 output rows

    __shared__ _Float16 s_pj[64 * 128];   // 16 KB (overlaid by comp bufs later)
    __shared__ _Float16 s_er[8][16 * 64]; // 16 KB, per-wave
    __shared__ _Float16 s_bm[64 * 72];    // 9 KB, padded rows
    __shared__ float    s_ai[16 * 64];    // 4 KB, A_i + rpb
    __shared__ _Float16 s_rb[128];        // reb1 (f16)
    __shared__ float    s_s0[64], s_s4[64];

    // ---- cooperative staging
    for (int idx = t; idx < 1024; idx += 512) {
        const int j = idx >> 4, g = idx & 15;
        const half8 v = *reinterpret_cast<const half8*>(
            P_h + (size_t)(bt * 64 + j) * 128 + g * 8);
        *reinterpret_cast<half8*>(&s_pj[j * 128 + ((g ^ (j & 7)) << 3)]) = v;
    }
    {
        const int j = t >> 3, c8 = (t & 7) * 8;
        if (t < 512)
            *reinterpret_cast<half8*>(&s_bm[j * 72 + c8]) =
                *reinterpret_cast<const half8*>(
                    Bh_g + (size_t)(bt * 64 + j) * 64 + c8);
    }
    for (int idx = t; idx < 1024; idx += 512) {
        const int il = idx >> 6, c = idx & 63;
        s_ai[idx] = A_g[(size_t)(rowb + il) * 64 + c] + rpb[c];
    }
    if (t < 128) s_rb[t] = (_Float16)reb1[t];
    if (t < 64) {
        const float* sp = &states[((size_t)((b * 64 + t) * 8 + tstep)) * 8];
        s_s0[t] = sp[0];
        s_s4[t] = sp[4];
    }

    // ---- per-wave weight fragments (f16, L2-hot)
    half8 w2f[4][4];
    #pragma unroll
    for (int kt = 0; kt < 4; ++kt)
        #pragma unroll
        for (int ct = 0; ct < 4; ++ct)
            w2f[kt][ct] = *reinterpret_cast<const half8*>(
                W2f + ((size_t)((kt * 4 + ct) * 64 + lane)) * 8);
    half8 wbf[2][4];
    #pragma unroll
    for (int kt = 0; kt < 2; ++kt)
        #pragma unroll
        for (int ct = 0; ct < 4; ++ct)
            wbf[kt][ct] = *reinterpret_cast<const half8*>(
                Wbf + ((size_t)((kt * 4 + ct) * 64 + lane)) * 8);
    float reb2c[4];
    #pragma unroll
    for (int ct = 0; ct < 4; ++ct) reb2c[ct] = reb2[ct * 16 + lc];

    __syncthreads();

    _Float16* er = s_er[w];
    float rag2[2][4];                     // reduced rel_agg, valid on lr==0

    for (int q = 0; q < 2; ++q) {
        const int il = w * 2 + q;         // block-local i
        const int i  = ig * 16 + il;      // bt-local i
        const int isw = i & 7;

        // pib = P_i + reb1 (f16 packed)
        half8 pib[4];
        #pragma unroll
        for (int kt = 0; kt < 4; ++kt) {
            const int g = kt * 4 + lr;
            const half8 pv = *reinterpret_cast<const half8*>(
                &s_pj[i * 128 + ((g ^ isw) << 3)]);
            const half8 rb = *reinterpret_cast<const half8*>(&s_rb[g * 8]);
            pib[kt] = pv + rb;
        }
        float aic[4];
        #pragma unroll
        for (int ct = 0; ct < 4; ++ct) aic[ct] = s_ai[il * 64 + ct * 16 + lc];
        const unsigned long long selm = __ballot(
            fabsf(s_s0[i] - s_s0[lane]) > 0.1f ||
            fabsf(s_s4[i] - s_s4[lane]) > 0.1f);

        float ragg[4] = {0.f, 0.f, 0.f, 0.f};

        for (int jt = 0; jt < 4; ++jt) {
            const int j = jt * 16 + lc;              // A-frag row (sender)
            const int jsw = j & 7;
            // h = relu(pib - P_j), f16 packed, one b128 per kt
            half8 af[4];
            #pragma unroll
            for (int kt = 0; kt < 4; ++kt) {
                const int g = (kt * 4 + lr) ^ jsw;
                const half8 pj = *reinterpret_cast<const half8*>(
                    &s_pj[j * 128 + (g << 3)]);
                af[kt] = relu8(pib[kt] - pj);
            }
            // GEMM1 tile: er = relu(h @ reW2 + reb2)
            #pragma unroll
            for (int ct = 0; ct < 4; ++ct) {
                f32x4 acc = {reb2c[ct], reb2c[ct], reb2c[ct], reb2c[ct]};
                #pragma unroll
                for (int kt = 0; kt < 4; ++kt)
                    acc = __builtin_amdgcn_mfma_f32_16x16x32_f16(
                        af[kt], w2f[kt][ct], acc, 0, 0, 0);
                #pragma unroll
                for (int r = 0; r < 4; ++r) {
                    const int jj2 = lr * 4 + r;      // tile-local row
                    const int c = ct * 16 + lc;
                    er[jj2 * 64 + ((((c >> 3) ^ (jj2 & 7)) << 3) | (c & 7))] =
                        (_Float16)fmaxf(acc[r], 0.f);
                }
            }
            // GEMM2 tile + epilogue
            half8 a2[2];
            #pragma unroll
            for (int kt = 0; kt < 2; ++kt) {
                const int g = (kt * 4 + lr) ^ (lc & 7);
                a2[kt] = *reinterpret_cast<const half8*>(&er[lc * 64 + (g << 3)]);
            }
            #pragma unroll
            for (int ct = 0; ct < 4; ++ct) {
                f32x4 acc = {aic[ct], aic[ct], aic[ct], aic[ct]};
                #pragma unroll
                for (int kt = 0; kt < 2; ++kt)
                    acc = __builtin_amdgcn_mfma_f32_16x16x32_f16(
                        a2[kt], wbf[kt][ct], acc, 0, 0, 0);
                #pragma unroll
                for (int r = 0; r < 4; ++r) {
                    const int jj = jt * 16 + lr * 4 + r;
                    const float bm = (float)s_bm[jj * 72 + ct * 16 + lc];
                    float v = fmaxf(acc[r] + bm, 0.f);
                    v = ((selm >> jj) & 1ull) ? v : 0.f;
                    ragg[ct] += v;
                }
            }
        }
        // cross-lane reduce over lr groups
        #pragma unroll
        for (int ct = 0; ct < 4; ++ct) {
            ragg[ct] += __shfl_xor(ragg[ct], 16);
            ragg[ct] += __shfl_xor(ragg[ct], 32);
            rag2[q][ct] = ragg[ct];
        }
    }
    __syncthreads();   // all waves done with s_pj -> overlay comp buffers

    // ================= fused composed MLP3 (bf16) on this block's 16 rows
    __bf16* s_x  = reinterpret_cast<__bf16*>(s_pj);            // 16*256
    __bf16* s_h1 = s_x + 16 * 256;                             // 16*128
    __bf16* s_h2 = s_h1 + 16 * 128;                            // 16*128

    // stage x (granules 0..19) from x_g
    for (int idx = t; idx < 320; idx += 512) {
        const int j = idx / 20, g = idx - j * 20;
        const bf16x8 v = *reinterpret_cast<const bf16x8*>(
            x_g + (size_t)(rowb + j) * 160 + g * 8);
        *reinterpret_cast<bf16x8*>(&s_x[j * 256 + ((g ^ (j & 7)) << 3)]) = v;
    }
    // rel_agg from registers (granules 20..27)
    if (lr == 0) {
        #pragma unroll
        for (int q = 0; q < 2; ++q) {
            const int il = w * 2 + q;
            #pragma unroll
            for (int ct = 0; ct < 4; ++ct) {
                const int c = ct * 16 + lc;
                const int gg = 20 + (c >> 3);
                s_x[il * 256 + ((gg ^ (il & 7)) << 3) + (c & 7)] =
                    (__bf16)rag2[q][ct];
            }
        }
    }
    __syncthreads();

    // ---- layer 1: K=224; ct = w
    const int jr = lc;
    const int sw = lc & 7;
    bf16x8 xf[7];
    #pragma unroll
    for (int kt = 0; kt < 7; ++kt)
        xf[kt] = *reinterpret_cast<const bf16x8*>(
            &s_x[jr * 256 + (((kt * 4 + lr) ^ sw) << 3)]);
    {
        const int ct = w;
        const float bias = cb1[ct * 16 + lc];
        f32x4 acc = {bias, bias, bias, bias};
        #pragma unroll
        for (int kt = 0; kt < 7; ++kt) {
            const bf16x8 wf = *reinterpret_cast<const bf16x8*>(
                Wc1f + ((size_t)((kt * 8 + ct) * 64 + lane)) * 8);
            acc = __builtin_amdgcn_mfma_f32_16x16x32_bf16(xf[kt], wf, acc, 0, 0, 0);
        }
        #pragma unroll
        for (int r = 0; r < 4; ++r) {
            const int jj = lr * 4 + r;
            const int col = ct * 16 + lc, g = col >> 3;
            s_h1[jj * 128 + (((g ^ (jj & 7)) << 3) | (col & 7))] =
                (__bf16)fmaxf(acc[r], 0.f);
        }
    }
    __syncthreads();

    // ---- layer 2: K=128; ct = w
    bf16x8 hf[4];
    #pragma unroll
    for (int kt = 0; kt < 4; ++kt)
        hf[kt] = *reinterpret_cast<const bf16x8*>(
            &s_h1[jr * 128 + (((kt * 4 + lr) ^ sw) << 3)]);
    {
        const int ct = w;
        const float bias = cb2[ct * 16 + lc];
        f32x4 acc = {bias, bias, bias, bias};
        #pragma unroll
        for (int kt = 0; kt < 4; ++kt) {
            const bf16x8 wf = *reinterpret_cast<const bf16x8*>(
                Wc2f + ((size_t)((kt * 8 + ct) * 64 + lane)) * 8);
            acc = __builtin_amdgcn_mfma_f32_16x16x32_bf16(hf[kt], wf, acc, 0, 0, 0);
        }
        #pragma unroll
        for (int r = 0; r < 4; ++r) {
            const int jj = lr * 4 + r;
            const int col = ct * 16 + lc, g = col >> 3;
            s_h2[jj * 128 + (((g ^ (jj & 7)) << 3) | (col & 7))] =
                (__bf16)fmaxf(acc[r], 0.f);
        }
    }
    __syncthreads();

    // ---- layer 3: K=128, N=32, no relu; waves 0,1
    if (w < 2) {
        bf16x8 h2f[4];
        #pragma unroll
        for (int kt = 0; kt < 4; ++kt)
            h2f[kt] = *reinterpret_cast<const bf16x8*>(
                &s_h2[jr * 128 + (((kt * 4 + lr) ^ sw) << 3)]);
        const int ct = w;
        const float bias = cb3[ct * 16 + lc];
        f32x4 acc = {bias, bias, bias, bias};
        #pragma unroll
        for (int kt = 0; kt < 4; ++kt) {
            const bf16x8 wf = *reinterpret_cast<const bf16x8*>(
                Wc3f + ((size_t)((kt * 2 + ct) * 64 + lane)) * 8);
            acc = __builtin_amdgcn_mfma_f32_16x16x32_bf16(h2f[kt], wf, acc, 0, 0, 0);
        }
        #pragma unroll
        for (int r = 0; r < 4; ++r) {
            const int rg = rowb + lr * 4 + r;
            out[(size_t)rg * 32 + ct * 16 + lc] = acc[r];
        }
    }
}

// ---------------------------------------------------------------- launch
extern "C" void kernel_launch(void* const* d_in, const int* in_sizes, int n_in,
                              void* d_out, int out_size, void* d_ws, size_t ws_size,
                              hipStream_t stream) {
    const float* states = (const float*)d_in[0];
    const float* sW1  = (const float*)d_in[2];
    const float* sb1  = (const float*)d_in[3];
    const float* sW2  = (const float*)d_in[4];
    const float* sb2  = (const float*)d_in[5];
    const float* uW1  = (const float*)d_in[6];
    const float* ub1  = (const float*)d_in[7];
    const float* uW2  = (const float*)d_in[8];
    const float* ub2  = (const float*)d_in[9];
    const float* upW  = (const float*)d_in[10];
    const float* upb  = (const float*)d_in[11];
    const float* reW1 = (const float*)d_in[12];
    const float* reb1 = (const float*)d_in[13];
    const float* reW2 = (const float*)d_in[14];
    const float* reb2 = (const float*)d_in[15];
    const float* rpW  = (const float*)d_in[16];
    const float* rpb  = (const float*)d_in[17];
    const float* cW1  = (const float*)d_in[18];
    const float* cb1  = (const float*)d_in[19];
    const float* cW2  = (const float*)d_in[20];
    const float* cb2  = (const float*)d_in[21];
    const float* cW3  = (const float*)d_in[22];
    const float* cb3  = (const float*)d_in[23];
    float* out = (float*)d_out;

    float* ws = (float*)d_ws;
    float* A_g = ws;                                  // 8192*64 f32
    _Float16* P_h  = (_Float16*)(A_g + 8192 * 64);    // 8192*128
    _Float16* Bh_g = P_h + 8192 * 128;                // 8192*64
    _Float16* W2f  = Bh_g + 8192 * 64;                // 16*512
    _Float16* Wbf  = W2f + 16 * 512;                  // 8*512
    __bf16* x_g  = (__bf16*)(Wbf + 8 * 512);          // 8192*160
    __bf16* Wl1f = x_g + 8192 * 160;                  // 24*512
    __bf16* Ws2f = Wl1f + 24 * 512;                   // 32*512
    __bf16* Wu2f = Ws2f + 32 * 512;                   // 8*512
    __bf16* Wupf = Wu2f + 8 * 512;                    // 10*512
    __bf16* Wabf = Wupf + 10 * 512;                   // 32*512
    __bf16* Wc1f = Wabf + 32 * 512;                   // 56*512
    __bf16* Wc2f = Wc1f + 56 * 512;                   // 32*512
    __bf16* Wc3f = Wc2f + 32 * 512;                   // 8*512

    k_prep<<<64, 256, 0, stream>>>(sW1, uW1, reW1, sW2, uW2, upW, reW2, rpW,
                                   cW1, cW2, cW3,
                                   Wl1f, Ws2f, Wu2f, Wupf, Wabf, W2f, Wbf,
                                   Wc1f, Wc2f, Wc3f);
    k_node<<<512, 512, 0, stream>>>(states, sb1, sb2, ub1, ub2, upb,
                                    Wl1f, Ws2f, Wu2f, Wupf, Wabf,
                                    P_h, A_g, Bh_g, x_g);
    k_pairc<<<512, 512, 0, stream>>>(states, P_h, A_g, Bh_g, x_g,
                                     reb1, reb2, rpb, W2f, Wbf,
                                     cb1, cb2, cb3, Wc1f, Wc2f, Wc3f, out);
}